// Round 6
// baseline (273.853 us; speedup 1.0000x reference)
//
#include <hip/hip_runtime.h>
#include <math.h>

#define NN 20000
#define NE 320000
#define NREL 9
#define NBASES 9
#define D_IN 128
#define D_HID 256
#define D_OUT 64
#define LN_EPS 1e-5f

#define N1 (NREL * D_HID + D_HID)   // 2560
#define N2 (NREL * D_OUT + D_OUT)   // 640
#define NBLK ((NN + 255) / 256)

typedef __attribute__((ext_vector_type(8))) short bf16x8;
typedef __attribute__((ext_vector_type(4))) float f32x4;

__device__ inline ushort f2b(float f) {
    unsigned u = __float_as_uint(f);
    return (ushort)((u + 0x7FFFu + ((u >> 16) & 1u)) >> 16);
}
__device__ inline float b2f(ushort h) { return __uint_as_float(((unsigned)h) << 16); }
__device__ inline unsigned pack2bf(float f0, float f1) {
    return (unsigned)f2b(f0) | ((unsigned)f2b(f1) << 16);
}

// ---------- fused prep: w1t, w2t (basis-combined, transposed, bf16) + x cast ----------
__global__ __launch_bounds__(256) void prep_all(
    const float* __restrict__ bases1, const float* __restrict__ comp1, const float* __restrict__ root1,
    const float* __restrict__ bases2, const float* __restrict__ comp2, const float* __restrict__ root2,
    const float* __restrict__ x,
    ushort* __restrict__ w1t, ushort* __restrict__ w2t, ushort* __restrict__ xbf)
{
    const int SZ1 = N1 * D_IN;
    const int SZ2 = N2 * D_HID;
    const int SZX = NN * D_IN;
    int tid = blockIdx.x * 256 + threadIdx.x;
    if (tid < SZ1) {
        int n = tid >> 7, k = tid & 127;
        float s;
        if (n < NREL * D_HID) {
            int r = n >> 8, o = n & 255;
            s = 0.f;
            #pragma unroll
            for (int b = 0; b < NBASES; b++)
                s += comp1[r * NBASES + b] * bases1[(b * D_IN + k) * D_HID + o];
        } else {
            s = root1[k * D_HID + (n - NREL * D_HID)];
        }
        w1t[tid] = f2b(s);
    } else if (tid < SZ1 + SZ2) {
        int j = tid - SZ1;
        int n = j >> 8, k = j & 255;
        float s;
        if (n < NREL * D_OUT) {
            int r = n >> 6, o = n & 63;
            s = 0.f;
            #pragma unroll
            for (int b = 0; b < NBASES; b++)
                s += comp2[r * NBASES + b] * bases2[(b * D_HID + k) * D_OUT + o];
        } else {
            s = root2[k * D_OUT + (n - NREL * D_OUT)];
        }
        w2t[j] = f2b(s);
    } else if (tid < SZ1 + SZ2 + SZX) {
        int j = tid - SZ1 - SZ2;
        xbf[j] = f2b(x[j]);
    }
}

// ---------- CSR build ----------
__global__ __launch_bounds__(256) void hist_dst(const int* __restrict__ dst, int* __restrict__ deg)
{
    int e = blockIdx.x * 256 + threadIdx.x;
    if (e < NE) atomicAdd(&deg[dst[e]], 1);
}

__global__ __launch_bounds__(256) void scan_blk(
    const int* __restrict__ deg, int* __restrict__ local, int* __restrict__ bsum)
{
    __shared__ int wsum[4];
    int tid = threadIdx.x, lane = tid & 63, w = tid >> 6;
    int i = blockIdx.x * 256 + tid;
    int v = (i < NN) ? deg[i] : 0;
    int x = v;
    #pragma unroll
    for (int d = 1; d < 64; d <<= 1) {
        int y = __shfl_up(x, d, 64);
        if (lane >= d) x += y;
    }
    if (lane == 63) wsum[w] = x;
    __syncthreads();
    int woff = 0;
    for (int j = 0; j < w; j++) woff += wsum[j];
    if (i < NN) local[i] = woff + x - v;
    if (tid == 255) bsum[blockIdx.x] = woff + x;
}

__global__ __launch_bounds__(64) void scan_top(const int* __restrict__ bsum, int* __restrict__ boff)
{
    int lane = threadIdx.x;
    int carry = 0;
    for (int base = 0; base < NBLK; base += 64) {
        int i = base + lane;
        int v = (i < NBLK) ? bsum[i] : 0;
        int x = v;
        #pragma unroll
        for (int d = 1; d < 64; d <<= 1) {
            int y = __shfl_up(x, d, 64);
            if (lane >= d) x += y;
        }
        if (i < NBLK) boff[i] = carry + x - v;
        carry += __shfl(x, 63, 64);
    }
}

__global__ __launch_bounds__(256) void scan_fin(
    const int* __restrict__ local, const int* __restrict__ boff,
    int* __restrict__ offs, int* __restrict__ cursor)
{
    int i = blockIdx.x * 256 + threadIdx.x;
    if (i < NN) {
        int o = local[i] + boff[i >> 8];
        offs[i] = o;
        cursor[i] = o;
    }
    if (i == NN) offs[NN] = NE;
}

__global__ __launch_bounds__(256) void scatter_ep(
    const int* __restrict__ src, const int* __restrict__ dst, const int* __restrict__ etype,
    int* __restrict__ cursor, int* __restrict__ ep1, int* __restrict__ ep2)
{
    int e = blockIdx.x * 256 + threadIdx.x;
    if (e >= NE) return;
    int d = dst[e];
    int s = src[e], r = etype[e];
    int pos = atomicAdd(&cursor[d], 1);
    ep1[pos] = s * N1 + r * D_HID;
    ep2[pos] = s * N2 + r * D_OUT;
}

// ---------- bf16 MFMA GEMM: C[M][N] = A[M][K] @ Bt[N][K]^T ----------
// 128x128 tile, BK=32 (16 KB LDS total -> r4-level occupancy). Staging via
// global_load_lds width=16, LDS in fragment order: slot s = g*64 + lane,
// where g = 16-row group, lane = kc*16 + mr. DMA writes lane-contiguous
// (zero bank conflicts); frag read is ds_read_b128 at (g*64+lane)*16B.
// Staging addresses hoisted: pointers advance 64 B per K-chunk.
// Operand-swapped MFMA -> C^T tiles -> packed uint2 (8 B) stores.
__global__ __launch_bounds__(256) void gemm_bf16(
    const ushort* __restrict__ A, const ushort* __restrict__ Bt, ushort* __restrict__ C,
    int M, int N, int K)
{
    __shared__ ushort As[512 * 8];   // 8 KB
    __shared__ ushort Bs[512 * 8];   // 8 KB

    int tid = threadIdx.x;
    int lane = tid & 63, w = tid >> 6;
    int wm = w >> 1, wn = w & 1;
    int row0 = blockIdx.y * 128, col0 = blockIdx.x * 128;

    // per-lane staging source pointers (2 DMA insts per wave for A, 2 for B)
    int mr = lane & 15, kc = lane >> 4;
    const ushort* ga[2];
    const ushort* gb[2];
    #pragma unroll
    for (int j = 0; j < 2; j++) {
        int g = w * 2 + j;                       // row/col group 0..7
        int row = min(row0 + g * 16 + mr, M - 1); // clamp; extra rows unused at store
        ga[j] = &A[(size_t)row * K + kc * 8];
        int col = col0 + g * 16 + mr;             // N % 128 == 0
        gb[j] = &Bt[(size_t)col * K + kc * 8];
    }

    f32x4 acc[4][4];
    #pragma unroll
    for (int mt = 0; mt < 4; mt++)
        #pragma unroll
        for (int nt = 0; nt < 4; nt++)
            acc[mt][nt] = (f32x4){0.f, 0.f, 0.f, 0.f};

    for (int k0 = 0; k0 < K; k0 += 32) {
        #pragma unroll
        for (int j = 0; j < 2; j++) {
            int sbase = (w * 2 + j) * 64;        // wave-uniform LDS base
            __builtin_amdgcn_global_load_lds(
                (const __attribute__((address_space(1))) unsigned int*)ga[j],
                (__attribute__((address_space(3))) unsigned int*)&As[(size_t)sbase * 8],
                16, 0, 0);
            __builtin_amdgcn_global_load_lds(
                (const __attribute__((address_space(1))) unsigned int*)gb[j],
                (__attribute__((address_space(3))) unsigned int*)&Bs[(size_t)sbase * 8],
                16, 0, 0);
            ga[j] += 32;                          // advance one K-chunk (64 B)
            gb[j] += 32;
        }
        __syncthreads();

        bf16x8 af[4], bfr[4];
        #pragma unroll
        for (int mt = 0; mt < 4; mt++)
            af[mt] = *(const bf16x8*)&As[(size_t)(((wm * 4 + mt) * 64) + lane) * 8];
        #pragma unroll
        for (int nt = 0; nt < 4; nt++)
            bfr[nt] = *(const bf16x8*)&Bs[(size_t)(((wn * 4 + nt) * 64) + lane) * 8];
        #pragma unroll
        for (int mt = 0; mt < 4; mt++)
            #pragma unroll
            for (int nt = 0; nt < 4; nt++)
                acc[mt][nt] = __builtin_amdgcn_mfma_f32_16x16x32_bf16(
                    bfr[nt], af[mt], acc[mt][nt], 0, 0, 0);   // swapped: D = C^T tile
        __syncthreads();
    }

    // epilogue: lane holds C[row = lane&15][cols q*4..q*4+3] per tile
    int q = lane >> 4, cm = lane & 15;
    #pragma unroll
    for (int mt = 0; mt < 4; mt++) {
        int gr = row0 + wm * 64 + mt * 16 + cm;
        if (gr < M) {
            #pragma unroll
            for (int nt = 0; nt < 4; nt++) {
                int gc = col0 + wn * 64 + nt * 16 + q * 4;
                uint2 o;
                o.x = pack2bf(acc[mt][nt][0], acc[mt][nt][1]);
                o.y = pack2bf(acc[mt][nt][2], acc[mt][nt][3]);
                *(uint2*)&C[(size_t)gr * N + gc] = o;
            }
        }
    }
}

// ---------- gather1: max over in-edges + root + bias -> LN -> ReLU -> h (bf16) ----------
// 8x unrolled edge loop: 8 independent 512 B gathers in flight per wave.
__global__ __launch_bounds__(256) void gather1(
    const ushort* __restrict__ xw1, const int* __restrict__ offs, const int* __restrict__ ep1,
    const float* __restrict__ bias, const float* __restrict__ g, const float* __restrict__ b,
    ushort* __restrict__ h)
{
    int n = blockIdx.x * 4 + (threadIdx.x >> 6);
    if (n >= NN) return;
    int lane = threadIdx.x & 63;
    int lane4 = lane * 4;
    int e0 = __builtin_amdgcn_readfirstlane(offs[n]);
    int e1 = __builtin_amdgcn_readfirstlane(offs[n + 1]);

    float m0 = -INFINITY, m1 = -INFINITY, m2 = -INFINITY, m3 = -INFINITY;
    int e = e0;
    for (; e + 8 <= e1; e += 8) {
        int p[8];
        #pragma unroll
        for (int j = 0; j < 8; j++) p[j] = ep1[e + j];
        ushort4 v[8];
        #pragma unroll
        for (int j = 0; j < 8; j++) v[j] = *(const ushort4*)&xw1[(size_t)(p[j] + lane4)];
        #pragma unroll
        for (int j = 0; j < 8; j++) {
            m0 = fmaxf(m0, b2f(v[j].x)); m1 = fmaxf(m1, b2f(v[j].y));
            m2 = fmaxf(m2, b2f(v[j].z)); m3 = fmaxf(m3, b2f(v[j].w));
        }
    }
    for (; e + 2 <= e1; e += 2) {
        int pa = ep1[e], pb = ep1[e + 1];
        ushort4 va = *(const ushort4*)&xw1[(size_t)(pa + lane4)];
        ushort4 vb = *(const ushort4*)&xw1[(size_t)(pb + lane4)];
        m0 = fmaxf(m0, fmaxf(b2f(va.x), b2f(vb.x)));
        m1 = fmaxf(m1, fmaxf(b2f(va.y), b2f(vb.y)));
        m2 = fmaxf(m2, fmaxf(b2f(va.z), b2f(vb.z)));
        m3 = fmaxf(m3, fmaxf(b2f(va.w), b2f(vb.w)));
    }
    for (; e < e1; e++) {
        int p = ep1[e];
        ushort4 v = *(const ushort4*)&xw1[(size_t)(p + lane4)];
        m0 = fmaxf(m0, b2f(v.x)); m1 = fmaxf(m1, b2f(v.y));
        m2 = fmaxf(m2, b2f(v.z)); m3 = fmaxf(m3, b2f(v.w));
    }
    if (e1 == e0) { m0 = m1 = m2 = m3 = 0.f; }

    ushort4 rt = *(const ushort4*)&xw1[(size_t)n * N1 + NREL * D_HID + lane4];
    int c = lane4;
    float t0 = m0 + b2f(rt.x) + bias[c + 0];
    float t1 = m1 + b2f(rt.y) + bias[c + 1];
    float t2 = m2 + b2f(rt.z) + bias[c + 2];
    float t3 = m3 + b2f(rt.w) + bias[c + 3];

    float s = t0 + t1 + t2 + t3;
    float s2 = t0 * t0 + t1 * t1 + t2 * t2 + t3 * t3;
    #pragma unroll
    for (int m = 32; m >= 1; m >>= 1) {
        s  += __shfl_xor(s,  m, 64);
        s2 += __shfl_xor(s2, m, 64);
    }
    float mu = s * (1.f / D_HID);
    float var = s2 * (1.f / D_HID) - mu * mu;
    float rs = rsqrtf(var + LN_EPS);

    ushort4 o;
    o.x = f2b(fmaxf((t0 - mu) * rs * g[c + 0] + b[c + 0], 0.f));
    o.y = f2b(fmaxf((t1 - mu) * rs * g[c + 1] + b[c + 1], 0.f));
    o.z = f2b(fmaxf((t2 - mu) * rs * g[c + 2] + b[c + 2], 0.f));
    o.w = f2b(fmaxf((t3 - mu) * rs * g[c + 3] + b[c + 3], 0.f));
    *(ushort4*)&h[(size_t)n * D_HID + c] = o;
}

// ---------- gather2: sum over in-edges + root + bias -> LN -> log_softmax -> out ----------
__global__ __launch_bounds__(256) void gather2(
    const ushort* __restrict__ xw2, const int* __restrict__ offs, const int* __restrict__ ep2,
    const float* __restrict__ bias, const float* __restrict__ g, const float* __restrict__ b,
    float* __restrict__ out)
{
    int n = blockIdx.x * 4 + (threadIdx.x >> 6);
    if (n >= NN) return;
    int lane = threadIdx.x & 63;
    int e0 = __builtin_amdgcn_readfirstlane(offs[n]);
    int e1 = __builtin_amdgcn_readfirstlane(offs[n + 1]);

    float s = 0.f;
    int e = e0;
    for (; e + 4 <= e1; e += 4) {
        int p0 = ep2[e + 0], p1 = ep2[e + 1], p2 = ep2[e + 2], p3 = ep2[e + 3];
        float a0 = b2f(xw2[(size_t)(p0 + lane)]);
        float a1 = b2f(xw2[(size_t)(p1 + lane)]);
        float a2 = b2f(xw2[(size_t)(p2 + lane)]);
        float a3 = b2f(xw2[(size_t)(p3 + lane)]);
        s += (a0 + a1) + (a2 + a3);
    }
    for (; e < e1; e++) {
        s += b2f(xw2[(size_t)(ep2[e] + lane)]);
    }
    float v = s + b2f(xw2[(size_t)n * N2 + NREL * D_OUT + lane]) + bias[lane];

    float sm = v, s2 = v * v;
    #pragma unroll
    for (int m = 32; m >= 1; m >>= 1) {
        sm += __shfl_xor(sm, m, 64);
        s2 += __shfl_xor(s2, m, 64);
    }
    float mu = sm * (1.f / D_OUT);
    float var = s2 * (1.f / D_OUT) - mu * mu;
    float y = (v - mu) * rsqrtf(var + LN_EPS) * g[lane] + b[lane];

    float mx = y;
    #pragma unroll
    for (int m = 32; m >= 1; m >>= 1) mx = fmaxf(mx, __shfl_xor(mx, m, 64));
    float ex = __expf(y - mx);
    float se = ex;
    #pragma unroll
    for (int m = 32; m >= 1; m >>= 1) se += __shfl_xor(se, m, 64);
    out[(size_t)n * D_OUT + lane] = y - mx - logf(se);
}

extern "C" void kernel_launch(void* const* d_in, const int* in_sizes, int n_in,
                              void* d_out, int out_size, void* d_ws, size_t ws_size,
                              hipStream_t stream)
{
    const float* x      = (const float*)d_in[0];
    const int*   eidx   = (const int*)  d_in[1];
    const int*   etype  = (const int*)  d_in[2];
    const float* bases1 = (const float*)d_in[3];
    const float* comp1  = (const float*)d_in[4];
    const float* root1  = (const float*)d_in[5];
    const float* bias1  = (const float*)d_in[6];
    const float* g1     = (const float*)d_in[7];
    const float* b1     = (const float*)d_in[8];
    const float* bases2 = (const float*)d_in[9];
    const float* comp2  = (const float*)d_in[10];
    const float* root2  = (const float*)d_in[11];
    const float* bias2  = (const float*)d_in[12];
    const float* g2     = (const float*)d_in[13];
    const float* b2     = (const float*)d_in[14];

    const int* src = eidx;
    const int* dst = eidx + NE;

    char* p = (char*)d_ws;
    auto alloc = [&](size_t bytes) -> char* {
        char* r = p;
        p += (bytes + 255) & ~(size_t)255;
        return r;
    };
    ushort* xbf    = (ushort*)alloc((size_t)NN * D_IN * 2);
    ushort* w1t    = (ushort*)alloc((size_t)N1 * D_IN * 2);
    ushort* w2t    = (ushort*)alloc((size_t)N2 * D_HID * 2);
    ushort* xw1    = (ushort*)alloc((size_t)NN * N1 * 2);
    ushort* xw2    = (ushort*)alloc((size_t)NN * N2 * 2);
    ushort* h      = (ushort*)alloc((size_t)NN * D_HID * 2);
    int*    deg    = (int*)   alloc((size_t)NN * 4);
    int*    local  = (int*)   alloc((size_t)NN * 4);
    int*    bsum   = (int*)   alloc((size_t)NBLK * 4);
    int*    boff   = (int*)   alloc((size_t)NBLK * 4);
    int*    offs   = (int*)   alloc((size_t)(NN + 1) * 4);
    int*    cursor = (int*)   alloc((size_t)NN * 4);
    int*    ep1    = (int*)   alloc((size_t)NE * 4);
    int*    ep2    = (int*)   alloc((size_t)NE * 4);

    const int SZP = N1 * D_IN + N2 * D_HID + NN * D_IN;
    prep_all<<<(SZP + 255) / 256, 256, 0, stream>>>(
        bases1, comp1, root1, bases2, comp2, root2, x, w1t, w2t, xbf);

    hipMemsetAsync(deg, 0, (size_t)NN * 4, stream);
    hist_dst<<<(NE + 255) / 256, 256, 0, stream>>>(dst, deg);
    scan_blk<<<NBLK, 256, 0, stream>>>(deg, local, bsum);
    scan_top<<<1, 64, 0, stream>>>(bsum, boff);
    scan_fin<<<NBLK, 256, 0, stream>>>(local, boff, offs, cursor);
    scatter_ep<<<(NE + 255) / 256, 256, 0, stream>>>(src, dst, etype, cursor, ep1, ep2);

    gemm_bf16<<<dim3(N1 / 128, (NN + 127) / 128), 256, 0, stream>>>(xbf, w1t, xw1, NN, N1, D_IN);
    gather1<<<(NN + 3) / 4, 256, 0, stream>>>(xw1, offs, ep1, bias1, g1, b1, h);

    gemm_bf16<<<dim3(N2 / 128, (NN + 127) / 128), 256, 0, stream>>>(h, w2t, xw2, NN, N2, D_HID);
    gather2<<<(NN + 3) / 4, 256, 0, stream>>>(xw2, offs, ep2, bias2, g2, b2, (float*)d_out);
}

// Round 7
// 256.558 us; speedup vs baseline: 1.0674x; 1.0674x over previous
//
#include <hip/hip_runtime.h>
#include <math.h>

#define NN 20000
#define NE 320000
#define NREL 9
#define NBASES 9
#define D_IN 128
#define D_HID 256
#define D_OUT 64
#define LN_EPS 1e-5f

#define N1 (NREL * D_HID + D_HID)   // 2560
#define N2 (NREL * D_OUT + D_OUT)   // 640
#define NBLK ((NN + 255) / 256)

#define LSTR 40                     // LDS row stride in ushorts (80 B): 2-way banks both sides

typedef __attribute__((ext_vector_type(8))) short bf16x8;
typedef __attribute__((ext_vector_type(4))) float f32x4;

__device__ inline ushort f2b(float f) {
    unsigned u = __float_as_uint(f);
    return (ushort)((u + 0x7FFFu + ((u >> 16) & 1u)) >> 16);
}
__device__ inline float b2f(ushort h) { return __uint_as_float(((unsigned)h) << 16); }
__device__ inline unsigned pack2bf(float f0, float f1) {
    return (unsigned)f2b(f0) | ((unsigned)f2b(f1) << 16);
}

// ---------- fused prep: w1t, w2t (basis-combined, transposed, bf16) + x cast ----------
__global__ __launch_bounds__(256) void prep_all(
    const float* __restrict__ bases1, const float* __restrict__ comp1, const float* __restrict__ root1,
    const float* __restrict__ bases2, const float* __restrict__ comp2, const float* __restrict__ root2,
    const float* __restrict__ x,
    ushort* __restrict__ w1t, ushort* __restrict__ w2t, ushort* __restrict__ xbf)
{
    const int SZ1 = N1 * D_IN;
    const int SZ2 = N2 * D_HID;
    const int SZX = NN * D_IN;
    int tid = blockIdx.x * 256 + threadIdx.x;
    if (tid < SZ1) {
        int n = tid >> 7, k = tid & 127;
        float s;
        if (n < NREL * D_HID) {
            int r = n >> 8, o = n & 255;
            s = 0.f;
            #pragma unroll
            for (int b = 0; b < NBASES; b++)
                s += comp1[r * NBASES + b] * bases1[(b * D_IN + k) * D_HID + o];
        } else {
            s = root1[k * D_HID + (n - NREL * D_HID)];
        }
        w1t[tid] = f2b(s);
    } else if (tid < SZ1 + SZ2) {
        int j = tid - SZ1;
        int n = j >> 8, k = j & 255;
        float s;
        if (n < NREL * D_OUT) {
            int r = n >> 6, o = n & 63;
            s = 0.f;
            #pragma unroll
            for (int b = 0; b < NBASES; b++)
                s += comp2[r * NBASES + b] * bases2[(b * D_HID + k) * D_OUT + o];
        } else {
            s = root2[k * D_OUT + (n - NREL * D_OUT)];
        }
        w2t[j] = f2b(s);
    } else if (tid < SZ1 + SZ2 + SZX) {
        int j = tid - SZ1 - SZ2;
        xbf[j] = f2b(x[j]);
    }
}

// ---------- CSR build ----------
__global__ __launch_bounds__(256) void hist_dst(const int* __restrict__ dst, int* __restrict__ deg)
{
    int e = blockIdx.x * 256 + threadIdx.x;
    if (e < NE) atomicAdd(&deg[dst[e]], 1);
}

__global__ __launch_bounds__(256) void scan_blk(
    const int* __restrict__ deg, int* __restrict__ local, int* __restrict__ bsum)
{
    __shared__ int wsum[4];
    int tid = threadIdx.x, lane = tid & 63, w = tid >> 6;
    int i = blockIdx.x * 256 + tid;
    int v = (i < NN) ? deg[i] : 0;
    int x = v;
    #pragma unroll
    for (int d = 1; d < 64; d <<= 1) {
        int y = __shfl_up(x, d, 64);
        if (lane >= d) x += y;
    }
    if (lane == 63) wsum[w] = x;
    __syncthreads();
    int woff = 0;
    for (int j = 0; j < w; j++) woff += wsum[j];
    if (i < NN) local[i] = woff + x - v;
    if (tid == 255) bsum[blockIdx.x] = woff + x;
}

__global__ __launch_bounds__(64) void scan_top(const int* __restrict__ bsum, int* __restrict__ boff)
{
    int lane = threadIdx.x;
    int carry = 0;
    for (int base = 0; base < NBLK; base += 64) {
        int i = base + lane;
        int v = (i < NBLK) ? bsum[i] : 0;
        int x = v;
        #pragma unroll
        for (int d = 1; d < 64; d <<= 1) {
            int y = __shfl_up(x, d, 64);
            if (lane >= d) x += y;
        }
        if (i < NBLK) boff[i] = carry + x - v;
        carry += __shfl(x, 63, 64);
    }
}

__global__ __launch_bounds__(256) void scan_fin(
    const int* __restrict__ local, const int* __restrict__ boff,
    int* __restrict__ offs, int* __restrict__ cursor)
{
    int i = blockIdx.x * 256 + threadIdx.x;
    if (i < NN) {
        int o = local[i] + boff[i >> 8];
        offs[i] = o;
        cursor[i] = o;
    }
    if (i == NN) offs[NN] = NE;
}

__global__ __launch_bounds__(256) void scatter_ep(
    const int* __restrict__ src, const int* __restrict__ dst, const int* __restrict__ etype,
    int* __restrict__ cursor, int* __restrict__ ep1, int* __restrict__ ep2)
{
    int e = blockIdx.x * 256 + threadIdx.x;
    if (e >= NE) return;
    int d = dst[e];
    int s = src[e], r = etype[e];
    int pos = atomicAdd(&cursor[d], 1);
    ep1[pos] = s * N1 + r * D_HID;
    ep2[pos] = s * N2 + r * D_OUT;
}

// ---------- bf16 MFMA GEMM: C[M][N] = A[M][K] @ Bt[N][K]^T ----------
// 128x128 tile, BK=32, double-buffered LDS (one barrier per chunk).
// VGPR staging: global loads of chunk c+1 issue right after the barrier and
// overlap ds_read+MFMA of chunk c (compiler keeps them in flight until the
// ds_write at the bottom). LDS layout [r][q] with row stride 80 B: writer
// banks (20r+4q)%32 and reader banks (20*mr+4*kq)%32 are both <=2-way (free).
// Global loads coalesced (4 threads = 64 B per row). Operand-swapped MFMA
// gives C^T tiles -> each lane holds 4 consecutive cols -> uint2 stores.
__global__ __launch_bounds__(256) void gemm_bf16(
    const ushort* __restrict__ A, const ushort* __restrict__ Bt, ushort* __restrict__ C,
    int M, int N, int K)
{
    __shared__ ushort As[2][128 * LSTR];   // 10,240 B per buffer
    __shared__ ushort Bs[2][128 * LSTR];   // total 40,960 B

    int tid = threadIdx.x;
    int lane = tid & 63, w = tid >> 6;
    int wm = w >> 1, wn = w & 1;
    int row0 = blockIdx.y * 128, col0 = blockIdx.x * 128;

    // staging: item1 s=tid -> (r0,q0); item2 s=tid+256 -> (r0+64,q0)
    int r0 = tid >> 2, q0 = tid & 3;
    int arow0 = min(row0 + r0, M - 1);        // clamp; extra rows discarded at store
    int arow1 = min(row0 + r0 + 64, M - 1);
    const ushort* gA0 = &A[(size_t)arow0 * K + q0 * 8];
    const ushort* gA1 = &A[(size_t)arow1 * K + q0 * 8];
    const ushort* gB0 = &Bt[(size_t)(col0 + r0) * K + q0 * 8];        // N%128==0, no OOB
    const ushort* gB1 = &Bt[(size_t)(col0 + r0 + 64) * K + q0 * 8];
    int lo0 = r0 * LSTR + q0 * 8;
    int lo1 = (r0 + 64) * LSTR + q0 * 8;

    f32x4 acc[4][4];
    #pragma unroll
    for (int mt = 0; mt < 4; mt++)
        #pragma unroll
        for (int nt = 0; nt < 4; nt++)
            acc[mt][nt] = (f32x4){0.f, 0.f, 0.f, 0.f};

    // prologue: stage chunk 0 into buffer 0
    {
        bf16x8 a0 = *(const bf16x8*)gA0;
        bf16x8 a1 = *(const bf16x8*)gA1;
        bf16x8 b0 = *(const bf16x8*)gB0;
        bf16x8 b1 = *(const bf16x8*)gB1;
        *(bf16x8*)&As[0][lo0] = a0;
        *(bf16x8*)&As[0][lo1] = a1;
        *(bf16x8*)&Bs[0][lo0] = b0;
        *(bf16x8*)&Bs[0][lo1] = b1;
    }

    int mr = lane & 15, kq = lane >> 4;
    const int NC = K >> 5;
    for (int c = 0; c < NC; c++) {
        __syncthreads();
        int cur = c & 1, nxt = cur ^ 1;
        bf16x8 a0, a1, b0, b1;
        bool more = (c + 1 < NC);
        if (more) {
            gA0 += 32; gA1 += 32; gB0 += 32; gB1 += 32;
            a0 = *(const bf16x8*)gA0;
            a1 = *(const bf16x8*)gA1;
            b0 = *(const bf16x8*)gB0;
            b1 = *(const bf16x8*)gB1;
        }

        bf16x8 af[4], bfr[4];
        #pragma unroll
        for (int mt = 0; mt < 4; mt++)
            af[mt] = *(const bf16x8*)&As[cur][(wm * 64 + mt * 16 + mr) * LSTR + kq * 8];
        #pragma unroll
        for (int nt = 0; nt < 4; nt++)
            bfr[nt] = *(const bf16x8*)&Bs[cur][(wn * 64 + nt * 16 + mr) * LSTR + kq * 8];
        #pragma unroll
        for (int mt = 0; mt < 4; mt++)
            #pragma unroll
            for (int nt = 0; nt < 4; nt++)
                acc[mt][nt] = __builtin_amdgcn_mfma_f32_16x16x32_bf16(
                    bfr[nt], af[mt], acc[mt][nt], 0, 0, 0);   // swapped: D = C^T tile

        if (more) {
            *(bf16x8*)&As[nxt][lo0] = a0;
            *(bf16x8*)&As[nxt][lo1] = a1;
            *(bf16x8*)&Bs[nxt][lo0] = b0;
            *(bf16x8*)&Bs[nxt][lo1] = b1;
        }
    }

    // epilogue: lane holds C[row = lane&15][cols q*4..q*4+3] per tile
    int q = lane >> 4, cm = lane & 15;
    #pragma unroll
    for (int mt = 0; mt < 4; mt++) {
        int gr = row0 + wm * 64 + mt * 16 + cm;
        if (gr < M) {
            #pragma unroll
            for (int nt = 0; nt < 4; nt++) {
                int gc = col0 + wn * 64 + nt * 16 + q * 4;
                uint2 o;
                o.x = pack2bf(acc[mt][nt][0], acc[mt][nt][1]);
                o.y = pack2bf(acc[mt][nt][2], acc[mt][nt][3]);
                *(uint2*)&C[(size_t)gr * N + gc] = o;
            }
        }
    }
}

// ---------- gather1: max over in-edges + root + bias -> LN -> ReLU -> h (bf16) ----------
__global__ __launch_bounds__(256) void gather1(
    const ushort* __restrict__ xw1, const int* __restrict__ offs, const int* __restrict__ ep1,
    const float* __restrict__ bias, const float* __restrict__ g, const float* __restrict__ b,
    ushort* __restrict__ h)
{
    int n = blockIdx.x * 4 + (threadIdx.x >> 6);
    if (n >= NN) return;
    int lane = threadIdx.x & 63;
    int lane4 = lane * 4;
    int e0 = __builtin_amdgcn_readfirstlane(offs[n]);
    int e1 = __builtin_amdgcn_readfirstlane(offs[n + 1]);

    float m0 = -INFINITY, m1 = -INFINITY, m2 = -INFINITY, m3 = -INFINITY;
    int e = e0;
    for (; e + 8 <= e1; e += 8) {
        int p[8];
        #pragma unroll
        for (int j = 0; j < 8; j++) p[j] = ep1[e + j];
        ushort4 v[8];
        #pragma unroll
        for (int j = 0; j < 8; j++) v[j] = *(const ushort4*)&xw1[(size_t)(p[j] + lane4)];
        #pragma unroll
        for (int j = 0; j < 8; j++) {
            m0 = fmaxf(m0, b2f(v[j].x)); m1 = fmaxf(m1, b2f(v[j].y));
            m2 = fmaxf(m2, b2f(v[j].z)); m3 = fmaxf(m3, b2f(v[j].w));
        }
    }
    for (; e + 2 <= e1; e += 2) {
        int pa = ep1[e], pb = ep1[e + 1];
        ushort4 va = *(const ushort4*)&xw1[(size_t)(pa + lane4)];
        ushort4 vb = *(const ushort4*)&xw1[(size_t)(pb + lane4)];
        m0 = fmaxf(m0, fmaxf(b2f(va.x), b2f(vb.x)));
        m1 = fmaxf(m1, fmaxf(b2f(va.y), b2f(vb.y)));
        m2 = fmaxf(m2, fmaxf(b2f(va.z), b2f(vb.z)));
        m3 = fmaxf(m3, fmaxf(b2f(va.w), b2f(vb.w)));
    }
    for (; e < e1; e++) {
        int p = ep1[e];
        ushort4 v = *(const ushort4*)&xw1[(size_t)(p + lane4)];
        m0 = fmaxf(m0, b2f(v.x)); m1 = fmaxf(m1, b2f(v.y));
        m2 = fmaxf(m2, b2f(v.z)); m3 = fmaxf(m3, b2f(v.w));
    }
    if (e1 == e0) { m0 = m1 = m2 = m3 = 0.f; }

    ushort4 rt = *(const ushort4*)&xw1[(size_t)n * N1 + NREL * D_HID + lane4];
    int c = lane4;
    float t0 = m0 + b2f(rt.x) + bias[c + 0];
    float t1 = m1 + b2f(rt.y) + bias[c + 1];
    float t2 = m2 + b2f(rt.z) + bias[c + 2];
    float t3 = m3 + b2f(rt.w) + bias[c + 3];

    float s = t0 + t1 + t2 + t3;
    float s2 = t0 * t0 + t1 * t1 + t2 * t2 + t3 * t3;
    #pragma unroll
    for (int m = 32; m >= 1; m >>= 1) {
        s  += __shfl_xor(s,  m, 64);
        s2 += __shfl_xor(s2, m, 64);
    }
    float mu = s * (1.f / D_HID);
    float var = s2 * (1.f / D_HID) - mu * mu;
    float rs = rsqrtf(var + LN_EPS);

    ushort4 o;
    o.x = f2b(fmaxf((t0 - mu) * rs * g[c + 0] + b[c + 0], 0.f));
    o.y = f2b(fmaxf((t1 - mu) * rs * g[c + 1] + b[c + 1], 0.f));
    o.z = f2b(fmaxf((t2 - mu) * rs * g[c + 2] + b[c + 2], 0.f));
    o.w = f2b(fmaxf((t3 - mu) * rs * g[c + 3] + b[c + 3], 0.f));
    *(ushort4*)&h[(size_t)n * D_HID + c] = o;
}

// ---------- gather2: sum over in-edges + root + bias -> LN -> log_softmax -> out ----------
__global__ __launch_bounds__(256) void gather2(
    const ushort* __restrict__ xw2, const int* __restrict__ offs, const int* __restrict__ ep2,
    const float* __restrict__ bias, const float* __restrict__ g, const float* __restrict__ b,
    float* __restrict__ out)
{
    int n = blockIdx.x * 4 + (threadIdx.x >> 6);
    if (n >= NN) return;
    int lane = threadIdx.x & 63;
    int e0 = __builtin_amdgcn_readfirstlane(offs[n]);
    int e1 = __builtin_amdgcn_readfirstlane(offs[n + 1]);

    float s = 0.f;
    int e = e0;
    for (; e + 4 <= e1; e += 4) {
        int p0 = ep2[e + 0], p1 = ep2[e + 1], p2 = ep2[e + 2], p3 = ep2[e + 3];
        float a0 = b2f(xw2[(size_t)(p0 + lane)]);
        float a1 = b2f(xw2[(size_t)(p1 + lane)]);
        float a2 = b2f(xw2[(size_t)(p2 + lane)]);
        float a3 = b2f(xw2[(size_t)(p3 + lane)]);
        s += (a0 + a1) + (a2 + a3);
    }
    for (; e < e1; e++) {
        s += b2f(xw2[(size_t)(ep2[e] + lane)]);
    }
    float v = s + b2f(xw2[(size_t)n * N2 + NREL * D_OUT + lane]) + bias[lane];

    float sm = v, s2 = v * v;
    #pragma unroll
    for (int m = 32; m >= 1; m >>= 1) {
        sm += __shfl_xor(sm, m, 64);
        s2 += __shfl_xor(s2, m, 64);
    }
    float mu = sm * (1.f / D_OUT);
    float var = s2 * (1.f / D_OUT) - mu * mu;
    float y = (v - mu) * rsqrtf(var + LN_EPS) * g[lane] + b[lane];

    float mx = y;
    #pragma unroll
    for (int m = 32; m >= 1; m >>= 1) mx = fmaxf(mx, __shfl_xor(mx, m, 64));
    float ex = __expf(y - mx);
    float se = ex;
    #pragma unroll
    for (int m = 32; m >= 1; m >>= 1) se += __shfl_xor(se, m, 64);
    out[(size_t)n * D_OUT + lane] = y - mx - logf(se);
}

extern "C" void kernel_launch(void* const* d_in, const int* in_sizes, int n_in,
                              void* d_out, int out_size, void* d_ws, size_t ws_size,
                              hipStream_t stream)
{
    const float* x      = (const float*)d_in[0];
    const int*   eidx   = (const int*)  d_in[1];
    const int*   etype  = (const int*)  d_in[2];
    const float* bases1 = (const float*)d_in[3];
    const float* comp1  = (const float*)d_in[4];
    const float* root1  = (const float*)d_in[5];
    const float* bias1  = (const float*)d_in[6];
    const float* g1     = (const float*)d_in[7];
    const float* b1     = (const float*)d_in[8];
    const float* bases2 = (const float*)d_in[9];
    const float* comp2  = (const float*)d_in[10];
    const float* root2  = (const float*)d_in[11];
    const float* bias2  = (const float*)d_in[12];
    const float* g2     = (const float*)d_in[13];
    const float* b2     = (const float*)d_in[14];

    const int* src = eidx;
    const int* dst = eidx + NE;

    char* p = (char*)d_ws;
    auto alloc = [&](size_t bytes) -> char* {
        char* r = p;
        p += (bytes + 255) & ~(size_t)255;
        return r;
    };
    ushort* xbf    = (ushort*)alloc((size_t)NN * D_IN * 2);
    ushort* w1t    = (ushort*)alloc((size_t)N1 * D_IN * 2);
    ushort* w2t    = (ushort*)alloc((size_t)N2 * D_HID * 2);
    ushort* xw1    = (ushort*)alloc((size_t)NN * N1 * 2);
    ushort* xw2    = (ushort*)alloc((size_t)NN * N2 * 2);
    ushort* h      = (ushort*)alloc((size_t)NN * D_HID * 2);
    int*    deg    = (int*)   alloc((size_t)NN * 4);
    int*    local  = (int*)   alloc((size_t)NN * 4);
    int*    bsum   = (int*)   alloc((size_t)NBLK * 4);
    int*    boff   = (int*)   alloc((size_t)NBLK * 4);
    int*    offs   = (int*)   alloc((size_t)(NN + 1) * 4);
    int*    cursor = (int*)   alloc((size_t)NN * 4);
    int*    ep1    = (int*)   alloc((size_t)NE * 4);
    int*    ep2    = (int*)   alloc((size_t)NE * 4);

    const int SZP = N1 * D_IN + N2 * D_HID + NN * D_IN;
    prep_all<<<(SZP + 255) / 256, 256, 0, stream>>>(
        bases1, comp1, root1, bases2, comp2, root2, x, w1t, w2t, xbf);

    hipMemsetAsync(deg, 0, (size_t)NN * 4, stream);
    hist_dst<<<(NE + 255) / 256, 256, 0, stream>>>(dst, deg);
    scan_blk<<<NBLK, 256, 0, stream>>>(deg, local, bsum);
    scan_top<<<1, 64, 0, stream>>>(bsum, boff);
    scan_fin<<<NBLK, 256, 0, stream>>>(local, boff, offs, cursor);
    scatter_ep<<<(NE + 255) / 256, 256, 0, stream>>>(src, dst, etype, cursor, ep1, ep2);

    gemm_bf16<<<dim3(N1 / 128, (NN + 127) / 128), 256, 0, stream>>>(xbf, w1t, xw1, NN, N1, D_IN);
    gather1<<<(NN + 3) / 4, 256, 0, stream>>>(xw1, offs, ep1, bias1, g1, b1, h);

    gemm_bf16<<<dim3(N2 / 128, (NN + 127) / 128), 256, 0, stream>>>(h, w2t, xw2, NN, N2, D_HID);
    gather2<<<(NN + 3) / 4, 256, 0, stream>>>(xw2, offs, ep2, bias2, g2, b2, (float*)d_out);
}